// Round 14
// baseline (44.340 us; speedup 1.0000x reference)
//
#include <hip/hip_runtime.h>
#include <hip/hip_fp16.h>
#include <math.h>

// MultiHeadAttentionQuantum: analytic collapse of the 8-qubit circuit.
//   angles[t][n] = dot(x[t], w_q[n]) + q_params[n] ; c = cos(angles)
//   z[0] = c1..c7 ; z[w>=1] = c0..cw  (Heisenberg CNOT-ring push-through)
//   out[t][e] = sum_n z[n] * w_out[e][n]
//
// R14: R13 (36.1us, best) is LDS-bound at 3 blocks/CU (48 KB); VGPR 72
// permits 16 waves/CU. Single variable: weights stored fp16 in LDS
// (24 KB total), fp32 math via cvt on read. Numerics proven in R11
// (absmax 0.0156 <= 0.0578); R11's blowup was its bounds(256,6) squeeze,
// not precision. Keep bounds(256,4), 4 tok/wave, grid 2048, caching x
// loads, PLAIN stores (R13), circuit8.

using f32x4 = __attribute__((ext_vector_type(4))) float;

constexpr int E  = 768;
constexpr int NW = 8;
constexpr int BLOCK = 256;                      // 4 waves
constexpr int TOKENS = 16 * 2048;               // 32768
constexpr int TOK_PER_WAVE  = 4;
constexpr int TOK_PER_BLOCK = TOK_PER_WAVE * 4; // 16
constexpr int GRID = TOKENS / TOK_PER_BLOCK;    // 2048

// Wave-wide reduce of zf[0..7] + cos + CNOT-ring prefix products.
// Numerically verified R4-R13 (absmax 0.0078).
__device__ __forceinline__ void circuit8(const float zf[NW], int lane, float qpl,
                                         float z[NW]) {
    float v4[4];
    #pragma unroll
    for (int i = 0; i < 4; ++i) {
        float a = zf[2*i], b = zf[2*i+1];
        float keep = (lane & 1) ? b : a;
        float send = (lane & 1) ? a : b;
        v4[i] = keep + __shfl_xor(send, 1, 64);
    }
    float v2[2];
    #pragma unroll
    for (int i = 0; i < 2; ++i) {
        float a = v4[2*i], b = v4[2*i+1];
        float keep = (lane & 2) ? b : a;
        float send = (lane & 2) ? a : b;
        v2[i] = keep + __shfl_xor(send, 2, 64);
    }
    float a = v2[0], b = v2[1];
    float keep = (lane & 4) ? b : a;
    float send = (lane & 4) ? a : b;
    float v = keep + __shfl_xor(send, 4, 64);
    v += __shfl_xor(v, 8, 64);
    v += __shfl_xor(v, 16, 64);
    v += __shfl_xor(v, 32, 64);
    float c = __cosf(v + qpl);               // one cos per token (wire lane&7)
    float cx = __shfl_xor(c, 1, 64);
    float e0 = (lane & 1) ? cx : c;
    float e1 = (lane & 1) ? c : cx;
    float e0x = __shfl_xor(e0, 2, 64), e1x = __shfl_xor(e1, 2, 64);
    float f0 = (lane & 2) ? e0x : e0;
    float f1 = (lane & 2) ? e1x : e1;
    float f2 = (lane & 2) ? e0  : e0x;
    float f3 = (lane & 2) ? e1  : e1x;
    float f0x = __shfl_xor(f0, 4, 64), f1x = __shfl_xor(f1, 4, 64);
    float f2x = __shfl_xor(f2, 4, 64), f3x = __shfl_xor(f3, 4, 64);
    float c0 = (lane & 4) ? f0x : f0;
    float c1 = (lane & 4) ? f1x : f1;
    float c2 = (lane & 4) ? f2x : f2;
    float c3 = (lane & 4) ? f3x : f3;
    float c4 = (lane & 4) ? f0  : f0x;
    float c5 = (lane & 4) ? f1  : f1x;
    float c6 = (lane & 4) ? f2  : f2x;
    float c7 = (lane & 4) ? f3  : f3x;
    float p1 = c0*c1, p2 = p1*c2, p3 = p2*c3, p4 = p3*c4;
    float p5 = p4*c5, p6 = p5*c6, p7 = p6*c7;
    float s  = c1*c2*c3*c4*c5*c6*c7;
    z[0] = s;  z[1] = p1; z[2] = p2; z[3] = p3;
    z[4] = p4; z[5] = p5; z[6] = p6; z[7] = p7;
}

__global__ __launch_bounds__(BLOCK, 4)
void mhaq_kernel(const float* __restrict__ x,
                 const float* __restrict__ w_q,
                 const float* __restrict__ w_out,
                 const float* __restrict__ q_params,
                 float* __restrict__ out)
{
    __shared__ __align__(16) __half wq_lds[NW][E];   // 12 KB, w_q [n][e] fp16
    __shared__ __align__(16) __half wt_lds[NW][E];   // 12 KB, w_out^T [n][e] fp16

    const int tid  = threadIdx.x;
    const int wave = tid >> 6;
    const int lane = tid & 63;
    const int col  = lane * 4;
    const int t0   = blockIdx.x * TOK_PER_BLOCK + wave * TOK_PER_WAVE;

    // ---- x loads issued FIRST: HBM latency overlaps (L2-hit) staging ----
    f32x4 xv[TOK_PER_WAVE][3];
    #pragma unroll
    for (int tt = 0; tt < TOK_PER_WAVE; ++tt) {
        const f32x4* xp = reinterpret_cast<const f32x4*>(x + (size_t)(t0 + tt) * E);
        #pragma unroll
        for (int k = 0; k < 3; ++k)
            xv[tt][k] = xp[lane + k * 64];
    }

    // ---- stage weights once per block, fp32 -> fp16 ----
    {
        const f32x4* src = reinterpret_cast<const f32x4*>(w_q);
        __half2* dst = reinterpret_cast<__half2*>(&wq_lds[0][0]);
        #pragma unroll
        for (int r = 0; r < (NW * E / 4) / BLOCK; ++r) {
            int idx = tid + r * BLOCK;
            f32x4 v = src[idx];
            dst[idx * 2]     = __floats2half2_rn(v.x, v.y);
            dst[idx * 2 + 1] = __floats2half2_rn(v.z, v.w);
        }
    }
    {
        const f32x4* src = reinterpret_cast<const f32x4*>(w_out);
        #pragma unroll
        for (int r = 0; r < (NW * E / 4) / BLOCK; ++r) {
            int idx = tid + r * BLOCK;       // f32x4 index into [768][8]
            f32x4 v = src[idx];
            int e  = idx >> 1;               // two f32x4 per e-row
            int n0 = (idx & 1) * 4;
            wt_lds[n0 + 0][e] = __float2half(v.x);
            wt_lds[n0 + 1][e] = __float2half(v.y);
            wt_lds[n0 + 2][e] = __float2half(v.z);
            wt_lds[n0 + 3][e] = __float2half(v.w);
        }
    }
    const float qpl = q_params[lane & 7];
    __syncthreads();

    // ---- per-lane partial dots (w_q fp16 from LDS, 8B/lane uniform stride) ----
    float zf[TOK_PER_WAVE][NW];
    #pragma unroll
    for (int n = 0; n < NW; ++n) {
        const __half2* wp = reinterpret_cast<const __half2*>(&wq_lds[n][0]);
        const int h0 = lane * 2;                 // half2 index of element col
        float2 w0a = __half22float2(wp[h0]);
        float2 w0b = __half22float2(wp[h0 + 1]);
        float2 w1a = __half22float2(wp[h0 + 128]);
        float2 w1b = __half22float2(wp[h0 + 129]);
        float2 w2a = __half22float2(wp[h0 + 256]);
        float2 w2b = __half22float2(wp[h0 + 257]);
        #pragma unroll
        for (int tt = 0; tt < TOK_PER_WAVE; ++tt) {
            zf[tt][n] =
                  xv[tt][0].x*w0a.x + xv[tt][0].y*w0a.y + xv[tt][0].z*w0b.x + xv[tt][0].w*w0b.y
                + xv[tt][1].x*w1a.x + xv[tt][1].y*w1a.y + xv[tt][1].z*w1b.x + xv[tt][1].w*w1b.y
                + xv[tt][2].x*w2a.x + xv[tt][2].y*w2a.y + xv[tt][2].z*w2b.x + xv[tt][2].w*w2b.y;
        }
    }

    // ---- wave reduce + cos + prefix products ----
    float z[TOK_PER_WAVE][NW];
    #pragma unroll
    for (int tt = 0; tt < TOK_PER_WAVE; ++tt)
        circuit8(zf[tt], lane, qpl, z[tt]);

    // ---- epilogue: out[t][e] = sum_n z[n] * w_out[e][n] (w_out^T fp16 LDS),
    //      plain stores (R13) ----
    #pragma unroll
    for (int k = 0; k < 3; ++k) {
        const int e0 = k * 256 + col;
        float2 wa[NW], wb[NW];                 // w_out[e0..e0+3][n] split in two float2
        #pragma unroll
        for (int n = 0; n < NW; ++n) {
            const __half2* hp = reinterpret_cast<const __half2*>(&wt_lds[n][e0]);
            wa[n] = __half22float2(hp[0]);
            wb[n] = __half22float2(hp[1]);
        }
        #pragma unroll
        for (int tt = 0; tt < TOK_PER_WAVE; ++tt) {
            float ox = 0.f, oy = 0.f, oz = 0.f, ow = 0.f;
            #pragma unroll
            for (int n = 0; n < NW; ++n) {
                ox += z[tt][n] * wa[n].x;
                oy += z[tt][n] * wa[n].y;
                oz += z[tt][n] * wb[n].x;
                ow += z[tt][n] * wb[n].y;
            }
            f32x4 o; o.x = ox; o.y = oy; o.z = oz; o.w = ow;
            *reinterpret_cast<f32x4*>(out + (size_t)(t0 + tt) * E + e0) = o;
        }
    }
}

extern "C" void kernel_launch(void* const* d_in, const int* in_sizes, int n_in,
                              void* d_out, int out_size, void* d_ws, size_t ws_size,
                              hipStream_t stream) {
    const float* x        = (const float*)d_in[0];
    const float* w_q      = (const float*)d_in[1];
    const float* w_out    = (const float*)d_in[2];
    const float* q_params = (const float*)d_in[3];
    float* out = (float*)d_out;

    hipLaunchKernelGGL(mhaq_kernel, dim3(GRID), dim3(BLOCK), 0, stream,
                       x, w_q, w_out, q_params, out);
}

// Round 15
// 37.406 us; speedup vs baseline: 1.1854x; 1.1854x over previous
//
#include <hip/hip_runtime.h>
#include <math.h>

// MultiHeadAttentionQuantum: analytic collapse of the 8-qubit circuit.
//   angles[t][n] = dot(x[t], w_q[n]) + q_params[n] ; c = cos(angles)
//   z[0] = c1..c7 ; z[w>=1] = c0..cw  (Heisenberg CNOT-ring push-through)
//   out[t][e] = sum_n z[n] * w_out[e][n]
//
// R15: R14 (fp16 LDS) regressed via extra cvt+ds ops at HIGHER occupancy --
// 5th proof occupancy isn't the lever; per-wave critical path is. R13 kept
// (fp32 weights in 48KB LDS, plain stores, caching x loads, circuit8).
// Single change: split the 4 tokens into two 2-token half-pipelines --
// t2/t3 x-loads are issued between dot(t0,t1) and finish(t0,t1), so their
// HBM latency hides under ~1000cy of compute. Peak registers DROP (12 xv
// live instead of 24). Cost: w_q LDS reads 2x (cheap DS pipe).

using f32x4 = __attribute__((ext_vector_type(4))) float;

constexpr int E  = 768;
constexpr int NW = 8;
constexpr int BLOCK = 256;                      // 4 waves
constexpr int TOKENS = 16 * 2048;               // 32768
constexpr int TOK_PER_WAVE  = 4;
constexpr int TOK_PER_BLOCK = TOK_PER_WAVE * 4; // 16
constexpr int GRID = TOKENS / TOK_PER_BLOCK;    // 2048

__device__ __forceinline__ float dot12(const f32x4& a0, const f32x4& a1, const f32x4& a2,
                                       const f32x4& b0, const f32x4& b1, const f32x4& b2) {
    return a0.x*b0.x + a0.y*b0.y + a0.z*b0.z + a0.w*b0.w
         + a1.x*b1.x + a1.y*b1.y + a1.z*b1.z + a1.w*b1.w
         + a2.x*b2.x + a2.y*b2.y + a2.z*b2.z + a2.w*b2.w;
}

// Wave-wide reduce of zf[0..7] + cos + CNOT-ring prefix products.
// Numerically verified R4-R14 (absmax 0.0078).
__device__ __forceinline__ void circuit8(const float zf[NW], int lane, float qpl,
                                         float z[NW]) {
    float v4[4];
    #pragma unroll
    for (int i = 0; i < 4; ++i) {
        float a = zf[2*i], b = zf[2*i+1];
        float keep = (lane & 1) ? b : a;
        float send = (lane & 1) ? a : b;
        v4[i] = keep + __shfl_xor(send, 1, 64);
    }
    float v2[2];
    #pragma unroll
    for (int i = 0; i < 2; ++i) {
        float a = v4[2*i], b = v4[2*i+1];
        float keep = (lane & 2) ? b : a;
        float send = (lane & 2) ? a : b;
        v2[i] = keep + __shfl_xor(send, 2, 64);
    }
    float a = v2[0], b = v2[1];
    float keep = (lane & 4) ? b : a;
    float send = (lane & 4) ? a : b;
    float v = keep + __shfl_xor(send, 4, 64);
    v += __shfl_xor(v, 8, 64);
    v += __shfl_xor(v, 16, 64);
    v += __shfl_xor(v, 32, 64);
    float c = __cosf(v + qpl);               // one cos per token (wire lane&7)
    float cx = __shfl_xor(c, 1, 64);
    float e0 = (lane & 1) ? cx : c;
    float e1 = (lane & 1) ? c : cx;
    float e0x = __shfl_xor(e0, 2, 64), e1x = __shfl_xor(e1, 2, 64);
    float f0 = (lane & 2) ? e0x : e0;
    float f1 = (lane & 2) ? e1x : e1;
    float f2 = (lane & 2) ? e0  : e0x;
    float f3 = (lane & 2) ? e1  : e1x;
    float f0x = __shfl_xor(f0, 4, 64), f1x = __shfl_xor(f1, 4, 64);
    float f2x = __shfl_xor(f2, 4, 64), f3x = __shfl_xor(f3, 4, 64);
    float c0 = (lane & 4) ? f0x : f0;
    float c1 = (lane & 4) ? f1x : f1;
    float c2 = (lane & 4) ? f2x : f2;
    float c3 = (lane & 4) ? f3x : f3;
    float c4 = (lane & 4) ? f0  : f0x;
    float c5 = (lane & 4) ? f1  : f1x;
    float c6 = (lane & 4) ? f2  : f2x;
    float c7 = (lane & 4) ? f3  : f3x;
    float p1 = c0*c1, p2 = p1*c2, p3 = p2*c3, p4 = p3*c4;
    float p5 = p4*c5, p6 = p5*c6, p7 = p6*c7;
    float s  = c1*c2*c3*c4*c5*c6*c7;
    z[0] = s;  z[1] = p1; z[2] = p2; z[3] = p3;
    z[4] = p4; z[5] = p5; z[6] = p6; z[7] = p7;
}

__device__ __forceinline__ void load_x2(const float* __restrict__ x, int t0, int lane,
                                        f32x4 xv[2][3]) {
    #pragma unroll
    for (int tt = 0; tt < 2; ++tt) {
        const f32x4* xp = reinterpret_cast<const f32x4*>(x + (size_t)(t0 + tt) * E);
        #pragma unroll
        for (int k = 0; k < 3; ++k)
            xv[tt][k] = xp[lane + k * 64];
    }
}

__device__ __forceinline__ void dot2(const f32x4 xv[2][3], const float (*wq)[E], int col,
                                     float zf[2][NW]) {
    #pragma unroll
    for (int n = 0; n < NW; ++n) {
        const f32x4 w0 = *reinterpret_cast<const f32x4*>(&wq[n][col]);
        const f32x4 w1 = *reinterpret_cast<const f32x4*>(&wq[n][col + 256]);
        const f32x4 w2 = *reinterpret_cast<const f32x4*>(&wq[n][col + 512]);
        #pragma unroll
        for (int tt = 0; tt < 2; ++tt)
            zf[tt][n] = dot12(xv[tt][0], xv[tt][1], xv[tt][2], w0, w1, w2);
    }
}

__device__ __forceinline__ void finish2(float zf[2][NW], const float (*wt)[E],
                                        int t0, int lane, int col, float qpl,
                                        float* __restrict__ out) {
    float z[2][NW];
    #pragma unroll
    for (int tt = 0; tt < 2; ++tt)
        circuit8(zf[tt], lane, qpl, z[tt]);

    #pragma unroll
    for (int k = 0; k < 3; ++k) {
        const int e0 = k * 256 + col;
        f32x4 wv[NW];
        #pragma unroll
        for (int n = 0; n < NW; ++n)
            wv[n] = *reinterpret_cast<const f32x4*>(&wt[n][e0]);
        #pragma unroll
        for (int tt = 0; tt < 2; ++tt) {
            float ox = 0.f, oy = 0.f, oz = 0.f, ow = 0.f;
            #pragma unroll
            for (int n = 0; n < NW; ++n) {
                ox += z[tt][n] * wv[n].x;
                oy += z[tt][n] * wv[n].y;
                oz += z[tt][n] * wv[n].z;
                ow += z[tt][n] * wv[n].w;
            }
            f32x4 o; o.x = ox; o.y = oy; o.z = oz; o.w = ow;
            *reinterpret_cast<f32x4*>(out + (size_t)(t0 + tt) * E + e0) = o;
        }
    }
}

__global__ __launch_bounds__(BLOCK, 4)
void mhaq_kernel(const float* __restrict__ x,
                 const float* __restrict__ w_q,
                 const float* __restrict__ w_out,
                 const float* __restrict__ q_params,
                 float* __restrict__ out)
{
    __shared__ float wq_lds[NW][E];   // 24 KB, w_q as-is [n][e]
    __shared__ float wt_lds[NW][E];   // 24 KB, w_out transposed [n][e]

    const int tid  = threadIdx.x;
    const int wave = tid >> 6;
    const int lane = tid & 63;
    const int col  = lane * 4;
    const int t0   = blockIdx.x * TOK_PER_BLOCK + wave * TOK_PER_WAVE;

    // ---- half A (t0,t0+1) x loads first: HBM latency overlaps staging ----
    f32x4 xa[2][3];
    load_x2(x, t0, lane, xa);

    // ---- stage weights once per block ----
    {
        const f32x4* src = reinterpret_cast<const f32x4*>(w_q);
        f32x4* dst = reinterpret_cast<f32x4*>(&wq_lds[0][0]);
        #pragma unroll
        for (int r = 0; r < (NW * E / 4) / BLOCK; ++r)
            dst[tid + r * BLOCK] = src[tid + r * BLOCK];
    }
    {
        const f32x4* src = reinterpret_cast<const f32x4*>(w_out);
        #pragma unroll
        for (int r = 0; r < (NW * E / 4) / BLOCK; ++r) {
            int idx = tid + r * BLOCK;       // f32x4 index into [768][8]
            f32x4 v = src[idx];
            int e  = idx >> 1;               // two f32x4 per e-row
            int n0 = (idx & 1) * 4;
            wt_lds[n0 + 0][e] = v.x;
            wt_lds[n0 + 1][e] = v.y;
            wt_lds[n0 + 2][e] = v.z;
            wt_lds[n0 + 3][e] = v.w;
        }
    }
    const float qpl = q_params[lane & 7];
    __syncthreads();

    // ---- half A dot ----
    float zfa[2][NW];
    dot2(xa, wq_lds, col, zfa);

    // ---- half B (t0+2,t0+3) loads: latency hidden under finish2(A) ----
    f32x4 xb[2][3];
    load_x2(x, t0 + 2, lane, xb);

    // ---- half A finish (circuit + epilogue; stores mid-wave) ----
    finish2(zfa, wt_lds, t0, lane, col, qpl, out);

    // ---- half B dot + finish ----
    float zfb[2][NW];
    dot2(xb, wq_lds, col, zfb);
    finish2(zfb, wt_lds, t0 + 2, lane, col, qpl, out);
}

extern "C" void kernel_launch(void* const* d_in, const int* in_sizes, int n_in,
                              void* d_out, int out_size, void* d_ws, size_t ws_size,
                              hipStream_t stream) {
    const float* x        = (const float*)d_in[0];
    const float* w_q      = (const float*)d_in[1];
    const float* w_out    = (const float*)d_in[2];
    const float* q_params = (const float*)d_in[3];
    float* out = (float*)d_out;

    hipLaunchKernelGGL(mhaq_kernel, dim3(GRID), dim3(BLOCK), 0, stream,
                       x, w_q, w_out, q_params, out);
}